// Round 5
// baseline (406.682 us; speedup 1.0000x reference)
//
#include <hip/hip_runtime.h>
#include <math.h>

#define NVIEWS 1024
#define SS 64
#define DD 256
#define KAUG 320   // augmented K: 256 W-cols + 64 one-hot pe cols

typedef __bf16 bf16x8 __attribute__((ext_vector_type(8)));
typedef float f32x4 __attribute__((ext_vector_type(4)));
typedef unsigned short us4 __attribute__((ext_vector_type(4)));
typedef unsigned short us8 __attribute__((ext_vector_type(8)));
typedef unsigned int u32x4 __attribute__((ext_vector_type(4)));

// LDS layout (bytes). Strides 16B-aligned; row shift = 4 banks -> worst 2-way (free).
#define STR_W 264   // [64][256] bf16 buffers: row = 528B
#define STR_T 72    // [256][64] vpT and [64][64] P: row = 144B
#define OFF_A 0      // qp (33792) -> vpT (36864) -> gelu-out (33792)
#define OFF_B 36864  // kp (33792) -> attn-out (33792)
#define OFF_P 70656  // P (9216)
#define LDS_TOTAL 79872

// ws layout (shorts): Wq' [256][320] @0, Wk' @81920, Wv' @163840, Wo [256][256] @245760
#define WS_WQ 0
#define WS_WK 81920
#define WS_WV 163840
#define WS_WO 245760

__device__ __forceinline__ unsigned short f2bf(float f) {
    return (unsigned short)((__builtin_bit_cast(unsigned int, f) + 0x8000u) >> 16);
}
__device__ __forceinline__ float bf2f(unsigned short h) {
    unsigned int u = ((unsigned int)h) << 16;
    return __builtin_bit_cast(float, u);
}
__device__ __forceinline__ unsigned int packbf2(float lo, float hi) {
    unsigned int ul = __builtin_bit_cast(unsigned int, lo) + 0x8000u;
    unsigned int uh = __builtin_bit_cast(unsigned int, hi) + 0x8000u;
    return __builtin_amdgcn_perm(uh, ul, 0x07060302u);
}

__global__ void prep_kernel(const float* __restrict__ Wq, const float* __restrict__ Wk,
                            const float* __restrict__ Wv, const float* __restrict__ Wo,
                            unsigned short* __restrict__ ws) {
    int t = blockIdx.x * blockDim.x + threadIdx.x;  // 65536 threads
    int n = t >> 8, k = t & 255;
    ws[WS_WQ + n * KAUG + k] = f2bf(Wq[t]);
    ws[WS_WK + n * KAUG + k] = f2bf(Wk[t]);
    ws[WS_WV + n * KAUG + k] = f2bf(Wv[t]);
    ws[WS_WO + t]            = f2bf(Wo[t]);
    if (t < SS * DD) {
        // pe[j][n]: j = sample 0..63, n = dim 0..255
        int j = t >> 8, d = t & 255;
        float ang = (float)j * expf(-((float)(d >> 1)) * (9.210340371976184f / 128.0f));
        unsigned short pb = f2bf((d & 1) ? cosf(ang) : sinf(ang));
        ws[WS_WQ + d * KAUG + 256 + j] = pb;
        ws[WS_WK + d * KAUG + 256 + j] = pb;
        ws[WS_WV + d * KAUG + 256 + j] = pb;
    }
}

// A-fragment: 8 consecutive fp32 -> bf16x8 via 2 NON-TEMPORAL float4 loads + 4 packs.
// q/k/v are single-use streaming data: nt keeps them from evicting ws (weights) in L2.
#define LOAD_A_FRAG(dst, Xp, row, kk)                                          \
    {                                                                          \
        const f32x4* _p = (const f32x4*)((Xp) + (row) * DD + (kk));            \
        f32x4 _a = __builtin_nontemporal_load(_p);                             \
        f32x4 _b = __builtin_nontemporal_load(_p + 1);                         \
        u32x4 _w;                                                              \
        _w[0] = packbf2(_a.x, _a.y); _w[1] = packbf2(_a.z, _a.w);              \
        _w[2] = packbf2(_b.x, _b.y); _w[3] = packbf2(_b.z, _b.w);              \
        dst = __builtin_bit_cast(us8, _w);                                     \
    }

#define MFMA(d, a, b) d = __builtin_amdgcn_mfma_f32_16x16x32_bf16(             \
        __builtin_bit_cast(bf16x8, a), __builtin_bit_cast(bf16x8, b), d, 0, 0, 0)

// Projection with pe folded in: acc[4][4], rows mt*16+.., cols n0+nt*16+..
// pe-tail weight loads hoisted ABOVE the k-loop: +8 loads in flight early,
// removes the end-of-loop latency bubble. Weight loads stay cacheable (L2).
#define PROJECT(Xp, Wp)                                                        \
    us8 _tp0 = *(const us8*)((Wp) + (n0 + l) * KAUG + 256 + koff);             \
    us8 _tp1 = *(const us8*)((Wp) + (n0 + 16 + l) * KAUG + 256 + koff);        \
    us8 _tp2 = *(const us8*)((Wp) + (n0 + 32 + l) * KAUG + 256 + koff);        \
    us8 _tp3 = *(const us8*)((Wp) + (n0 + 48 + l) * KAUG + 256 + koff);        \
    us8 _tr0 = *(const us8*)((Wp) + (n0 + l) * KAUG + 288 + koff);             \
    us8 _tr1 = *(const us8*)((Wp) + (n0 + 16 + l) * KAUG + 288 + koff);        \
    us8 _tr2 = *(const us8*)((Wp) + (n0 + 32 + l) * KAUG + 288 + koff);        \
    us8 _tr3 = *(const us8*)((Wp) + (n0 + 48 + l) * KAUG + 288 + koff);        \
    _Pragma("unroll 2")                                                        \
    for (int k0 = 0; k0 < DD; k0 += 32) {                                      \
        us8 af0, af1, af2, af3, bq0, bq1, bq2, bq3;                            \
        LOAD_A_FRAG(af0, Xp, l, k0 + koff);                                    \
        LOAD_A_FRAG(af1, Xp, 16 + l, k0 + koff);                               \
        LOAD_A_FRAG(af2, Xp, 32 + l, k0 + koff);                               \
        LOAD_A_FRAG(af3, Xp, 48 + l, k0 + koff);                               \
        bq0 = *(const us8*)((Wp) + (n0 + l) * KAUG + k0 + koff);               \
        bq1 = *(const us8*)((Wp) + (n0 + 16 + l) * KAUG + k0 + koff);          \
        bq2 = *(const us8*)((Wp) + (n0 + 32 + l) * KAUG + k0 + koff);          \
        bq3 = *(const us8*)((Wp) + (n0 + 48 + l) * KAUG + k0 + koff);          \
        MFMA(acc[0][0], af0, bq0); MFMA(acc[0][1], af0, bq1);                  \
        MFMA(acc[0][2], af0, bq2); MFMA(acc[0][3], af0, bq3);                  \
        MFMA(acc[1][0], af1, bq0); MFMA(acc[1][1], af1, bq1);                  \
        MFMA(acc[1][2], af1, bq2); MFMA(acc[1][3], af1, bq3);                  \
        MFMA(acc[2][0], af2, bq0); MFMA(acc[2][1], af2, bq1);                  \
        MFMA(acc[2][2], af2, bq2); MFMA(acc[2][3], af2, bq3);                  \
        MFMA(acc[3][0], af3, bq0); MFMA(acc[3][1], af3, bq1);                  \
        MFMA(acc[3][2], af3, bq2); MFMA(acc[3][3], af3, bq3);                  \
    }                                                                          \
    {                                                                          \
        /* augmented pe tail: one-hot A (synthesized), weights preloaded. */   \
        MFMA(acc[0][0], idA, _tp0); MFMA(acc[0][1], idA, _tp1);                \
        MFMA(acc[0][2], idA, _tp2); MFMA(acc[0][3], idA, _tp3);                \
        MFMA(acc[1][0], idB, _tp0); MFMA(acc[1][1], idB, _tp1);                \
        MFMA(acc[1][2], idB, _tp2); MFMA(acc[1][3], idB, _tp3);                \
        MFMA(acc[2][0], idA, _tr0); MFMA(acc[2][1], idA, _tr1);                \
        MFMA(acc[2][2], idA, _tr2); MFMA(acc[2][3], idA, _tr3);                \
        MFMA(acc[3][0], idB, _tr0); MFMA(acc[3][1], idB, _tr1);                \
        MFMA(acc[3][2], idB, _tr2); MFMA(acc[3][3], idB, _tr3);                \
    }

#define ZERO_ACC                                                               \
    _Pragma("unroll")                                                          \
    for (int _i = 0; _i < 4; ++_i)                                             \
        _Pragma("unroll")                                                      \
        for (int _j = 0; _j < 4; ++_j) acc[_i][_j] = (f32x4){0.f, 0.f, 0.f, 0.f};

// Store acc as bf16 into dst[64][STR_W] (pe already folded in)
#define STORE_C(dst)                                                           \
    _Pragma("unroll")                                                          \
    for (int mt = 0; mt < 4; ++mt)                                             \
        _Pragma("unroll")                                                      \
        for (int nt = 0; nt < 4; ++nt) {                                       \
            int col = n0 + nt * 16 + l;                                        \
            _Pragma("unroll")                                                  \
            for (int r = 0; r < 4; ++r)                                        \
                (dst)[(mt * 16 + (quad << 2) + r) * STR_W + col] = f2bf(acc[mt][nt][r]); \
        }

// 512 threads = 8 waves. Wave-specialized phase overlap:
//   P1: waves 0-3 kp (cols wp*64) -> sB  ||  waves 4-7 qp -> sA
//   P2: waves 0-3 S+softmax -> sP        ||  waves 4-7 vp (registers only)
//   then vpT write (4-7), PV / Wo / epilogue split 8 ways (32-col chunks).
// LDS 79872 B -> 2 blocks/CU, 16 waves/CU.
__global__ __launch_bounds__(512, 4)
void attn_kernel(const float* __restrict__ qg_, const float* __restrict__ kg_,
                 const float* __restrict__ vg_, const unsigned short* __restrict__ ws,
                 const float* __restrict__ bo, float* __restrict__ outg) {
    __shared__ __attribute__((aligned(16))) char smem[LDS_TOTAL];
    unsigned short* sA = (unsigned short*)(smem + OFF_A);  // qp -> vpT -> gelu-out
    unsigned short* sB = (unsigned short*)(smem + OFF_B);  // kp -> attn-out
    unsigned short* sP = (unsigned short*)(smem + OFF_P);

    const unsigned short* Wq = ws + WS_WQ;
    const unsigned short* Wk = ws + WS_WK;
    const unsigned short* Wv = ws + WS_WV;
    const unsigned short* Wo = ws + WS_WO;

    const int tid  = threadIdx.x;
    const int w    = tid >> 6;        // wave 0..7
    const int wp   = w & 3;           // projection-wave id 0..3
    const int whi  = w >> 2;          // 0: kp/S-group, 1: qp/vp-group
    const int lane = tid & 63;
    const int quad = lane >> 4;
    const int l    = lane & 15;
    const int n0   = wp << 6;         // 64-col chunk for projections
    const int n0h  = w << 5;          // 32-col chunk for PV / Wo phases
    const int koff = quad << 3;

    // one-hot A fragments for the augmented pe tail (no loads):
    // idA: A[m_tile=l][j_local] = (j_local == l); idB: = (j_local == 16+l)
    unsigned int w1 = (l & 1) ? 0x3F800000u : 0x00003F80u;  // bf16 1.0 in hi/lo half
    int dw = (l >> 1) & 3;
    bool cA = (quad == (l >> 3));        // j_local = l in this quad's 8-col window
    bool cB = (quad == 2 + (l >> 3));    // j_local = 16+l
    u32x4 eA, eB;
    eA[0] = (cA && dw == 0) ? w1 : 0u; eA[1] = (cA && dw == 1) ? w1 : 0u;
    eA[2] = (cA && dw == 2) ? w1 : 0u; eA[3] = (cA && dw == 3) ? w1 : 0u;
    eB[0] = (cB && dw == 0) ? w1 : 0u; eB[1] = (cB && dw == 1) ? w1 : 0u;
    eB[2] = (cB && dw == 2) ? w1 : 0u; eB[3] = (cB && dw == 3) ? w1 : 0u;
    us8 idA = __builtin_bit_cast(us8, eA);
    us8 idB = __builtin_bit_cast(us8, eB);

    const size_t base = (size_t)blockIdx.x * (SS * DD);
    const float* qg = qg_ + base;
    const float* kg = kg_ + base;
    const float* vg = vg_ + base;
    float* og = outg + base;

    f32x4 acc[4][4];

    // ---- P1: kp (waves 0-3) -> sB  ||  qp (waves 4-7) -> sA ----
    {
        const float* X1          = whi ? qg : kg;
        const unsigned short* W1 = whi ? Wq : Wk;
        unsigned short* D1       = whi ? sA : sB;
        ZERO_ACC
        PROJECT(X1, W1)
        STORE_C(D1)
    }
    __syncthreads();  // B1: qp, kp visible

    // ---- P2: S = qp@kp^T + softmax (waves 0-3, q-rows w*16..w*16+15)
    //          || vp = v@Wv^T + pe in registers (waves 4-7, no LDS) ----
    if (whi == 0) {
        f32x4 s0 = {0.f,0.f,0.f,0.f}, s1 = {0.f,0.f,0.f,0.f};
        f32x4 s2 = {0.f,0.f,0.f,0.f}, s3 = {0.f,0.f,0.f,0.f};
        #pragma unroll
        for (int k0 = 0; k0 < DD; k0 += 32) {
            us8 a  = *(const us8*)(sA + (w * 16 + l) * STR_W + k0 + koff);
            us8 b0 = *(const us8*)(sB + (l) * STR_W + k0 + koff);
            us8 b1 = *(const us8*)(sB + (16 + l) * STR_W + k0 + koff);
            us8 b2 = *(const us8*)(sB + (32 + l) * STR_W + k0 + koff);
            us8 b3 = *(const us8*)(sB + (48 + l) * STR_W + k0 + koff);
            MFMA(s0, a, b0); MFMA(s1, a, b1); MFMA(s2, a, b2); MFMA(s3, a, b3);
        }
        #pragma unroll
        for (int r = 0; r < 4; ++r) {
            float v0 = s0[r] * 0.0625f, v1 = s1[r] * 0.0625f;
            float v2 = s2[r] * 0.0625f, v3 = s3[r] * 0.0625f;
            float mx = fmaxf(fmaxf(v0, v1), fmaxf(v2, v3));
            #pragma unroll
            for (int d = 1; d <= 8; d <<= 1) mx = fmaxf(mx, __shfl_xor(mx, d));
            float e0 = __expf(v0 - mx), e1 = __expf(v1 - mx);
            float e2 = __expf(v2 - mx), e3 = __expf(v3 - mx);
            float sm = e0 + e1 + e2 + e3;
            #pragma unroll
            for (int d = 1; d <= 8; d <<= 1) sm += __shfl_xor(sm, d);
            float inv = 1.0f / sm;
            int row = w * 16 + (quad << 2) + r;
            sP[row * STR_T + l]      = f2bf(e0 * inv);
            sP[row * STR_T + 16 + l] = f2bf(e1 * inv);
            sP[row * STR_T + 32 + l] = f2bf(e2 * inv);
            sP[row * STR_T + 48 + l] = f2bf(e3 * inv);
        }
    } else {
        ZERO_ACC
        PROJECT(vg, Wv)
    }
    __syncthreads();  // B2: S-phase LDS reads done (qp dead); sP complete

    // transpose-write vpT into sA [256][STR_T] (waves 4-7 only)
    if (whi) {
        #pragma unroll
        for (int mt = 0; mt < 4; ++mt)
            #pragma unroll
            for (int nt = 0; nt < 4; ++nt) {
                int col = n0 + nt * 16 + l;            // d index = vpT row
                int rbase = mt * 16 + (quad << 2);
                us4 pk;
                #pragma unroll
                for (int r = 0; r < 4; ++r)
                    pk[r] = f2bf(acc[mt][nt][r]);
                *(us4*)(sA + col * STR_T + rbase) = pk;   // 8B transpose write
            }
    }
    __syncthreads();  // B3: vpT visible

    // ---- attn-out = P @ vp -> sB (all 8 waves, cols n0h..n0h+31) ----
    {
        ZERO_ACC
        #pragma unroll
        for (int k0 = 0; k0 < 64; k0 += 32) {
            us8 a0 = *(const us8*)(sP + (l) * STR_T + k0 + koff);
            us8 a1 = *(const us8*)(sP + (16 + l) * STR_T + k0 + koff);
            us8 a2 = *(const us8*)(sP + (32 + l) * STR_T + k0 + koff);
            us8 a3 = *(const us8*)(sP + (48 + l) * STR_T + k0 + koff);
            us8 b0 = *(const us8*)(sA + (n0h + l) * STR_T + k0 + koff);
            us8 b1 = *(const us8*)(sA + (n0h + 16 + l) * STR_T + k0 + koff);
            MFMA(acc[0][0], a0, b0); MFMA(acc[0][1], a0, b1);
            MFMA(acc[1][0], a1, b0); MFMA(acc[1][1], a1, b1);
            MFMA(acc[2][0], a2, b0); MFMA(acc[2][1], a2, b1);
            MFMA(acc[3][0], a3, b0); MFMA(acc[3][1], a3, b1);
        }
        #pragma unroll
        for (int mt = 0; mt < 4; ++mt)
            #pragma unroll
            for (int nt = 0; nt < 2; ++nt) {
                int col = n0h + nt * 16 + l;
                #pragma unroll
                for (int r = 0; r < 4; ++r)
                    sB[(mt * 16 + (quad << 2) + r) * STR_W + col] = f2bf(acc[mt][nt][r]);
            }
    }
    __syncthreads();  // B4: attn-out visible; vpT reads done

    // ---- y' = gelu(attn-out @ Wo^T + bo) -> sA (all 8 waves, cols n0h) ----
    {
        ZERO_ACC
        #pragma unroll 2
        for (int k0 = 0; k0 < DD; k0 += 32) {
            us8 a0 = *(const us8*)(sB + (l) * STR_W + k0 + koff);
            us8 a1 = *(const us8*)(sB + (16 + l) * STR_W + k0 + koff);
            us8 a2 = *(const us8*)(sB + (32 + l) * STR_W + k0 + koff);
            us8 a3 = *(const us8*)(sB + (48 + l) * STR_W + k0 + koff);
            us8 b0 = *(const us8*)(Wo + (n0h + l) * DD + k0 + koff);
            us8 b1 = *(const us8*)(Wo + (n0h + 16 + l) * DD + k0 + koff);
            MFMA(acc[0][0], a0, b0); MFMA(acc[0][1], a0, b1);
            MFMA(acc[1][0], a1, b0); MFMA(acc[1][1], a1, b1);
            MFMA(acc[2][0], a2, b0); MFMA(acc[2][1], a2, b1);
            MFMA(acc[3][0], a3, b0); MFMA(acc[3][1], a3, b1);
        }
        #pragma unroll
        for (int nt = 0; nt < 2; ++nt) {
            int col = n0h + nt * 16 + l;
            float bias = bo[col];
            #pragma unroll
            for (int mt = 0; mt < 4; ++mt) {
                #pragma unroll
                for (int r = 0; r < 4; ++r) {
                    int row = mt * 16 + (quad << 2) + r;
                    float y = acc[mt][nt][r] + bias;
                    // tanh-approx GELU: 0.5y(1+tanh(u)) = y*sigmoid(2u), max dev ~3e-4
                    float u = 1.5957691216f * y * (1.0f + 0.044715f * y * y);
                    float g = y / (1.0f + __expf(-u));
                    sA[row * STR_W + col] = f2bf(g);
                }
            }
        }
    }
    __syncthreads();  // B5: gelu-out visible

    // ---- coalesced epilogue: out = gelu-out + q (512 threads, 8 iters) ----
    // q re-read + out store are streaming: non-temporal, keep L2 for weights.
    #pragma unroll
    for (int s = 0; s < 8; ++s) {
        int f = s * 2048 + tid * 4;
        int row = f >> 8, col = f & 255;
        us4 gb = *(const us4*)(sA + row * STR_W + col);
        f32x4 qv = __builtin_nontemporal_load((const f32x4*)(qg + f));
        f32x4 o;
        o.x = bf2f(gb[0]) + qv.x;
        o.y = bf2f(gb[1]) + qv.y;
        o.z = bf2f(gb[2]) + qv.z;
        o.w = bf2f(gb[3]) + qv.w;
        __builtin_nontemporal_store(o, (f32x4*)(og + f));
    }
}

extern "C" void kernel_launch(void* const* d_in, const int* in_sizes, int n_in,
                              void* d_out, int out_size, void* d_ws, size_t ws_size,
                              hipStream_t stream) {
    const float* q  = (const float*)d_in[0];
    const float* k  = (const float*)d_in[1];
    const float* v  = (const float*)d_in[2];
    const float* Wq = (const float*)d_in[3];
    const float* Wk = (const float*)d_in[4];
    const float* Wv = (const float*)d_in[5];
    const float* Wo = (const float*)d_in[6];
    const float* bo = (const float*)d_in[7];
    unsigned short* ws = (unsigned short*)d_ws;  // augmented bf16 weights (pe folded)

    prep_kernel<<<256, 256, 0, stream>>>(Wq, Wk, Wv, Wo, ws);
    attn_kernel<<<NVIEWS, 512, 0, stream>>>(q, k, v, ws, bo, (float*)d_out);
}

// Round 8
// 291.250 us; speedup vs baseline: 1.3963x; 1.3963x over previous
//
#include <hip/hip_runtime.h>
#include <math.h>

#define NVIEWS 1024
#define SS 64
#define DD 256
#define KAUG 320   // augmented K: 256 W-cols + 64 one-hot pe cols

typedef __bf16 bf16x8 __attribute__((ext_vector_type(8)));
typedef float f32x4 __attribute__((ext_vector_type(4)));
typedef unsigned short us4 __attribute__((ext_vector_type(4)));
typedef unsigned short us8 __attribute__((ext_vector_type(8)));
typedef unsigned int u32x4 __attribute__((ext_vector_type(4)));

// LDS layout (bytes). Strides 16B-aligned; row shift = 4 banks.
#define STR_W 264   // [64][256] bf16 buffers: row = 528B
#define STR_T 72    // [256][64] vpT and [64][64] P: row = 144B
#define OFF_A 0      // qbf -> qp -> vbf -> vpT -> gelu-out
#define OFF_B 36864  // kbf -> kp -> attn-out
#define OFF_P 70656  // P (9216)
#define LDS_TOTAL 79872

// ws layout (shorts): Wq' [256][320] @0, Wk' @81920, Wv' @163840, Wo [256][256] @245760
#define WS_WQ 0
#define WS_WK 81920
#define WS_WV 163840
#define WS_WO 245760

__device__ __forceinline__ unsigned short f2bf(float f) {
    return (unsigned short)((__builtin_bit_cast(unsigned int, f) + 0x8000u) >> 16);
}
__device__ __forceinline__ float bf2f(unsigned short h) {
    unsigned int u = ((unsigned int)h) << 16;
    return __builtin_bit_cast(float, u);
}
__device__ __forceinline__ unsigned int packbf2(float lo, float hi) {
    unsigned int ul = __builtin_bit_cast(unsigned int, lo) + 0x8000u;
    unsigned int uh = __builtin_bit_cast(unsigned int, hi) + 0x8000u;
    return __builtin_amdgcn_perm(uh, ul, 0x07060302u);
}

__global__ void prep_kernel(const float* __restrict__ Wq, const float* __restrict__ Wk,
                            const float* __restrict__ Wv, const float* __restrict__ Wo,
                            unsigned short* __restrict__ ws) {
    int t = blockIdx.x * blockDim.x + threadIdx.x;  // 65536 threads
    int n = t >> 8, k = t & 255;
    ws[WS_WQ + n * KAUG + k] = f2bf(Wq[t]);
    ws[WS_WK + n * KAUG + k] = f2bf(Wk[t]);
    ws[WS_WV + n * KAUG + k] = f2bf(Wv[t]);
    ws[WS_WO + t]            = f2bf(Wo[t]);
    if (t < SS * DD) {
        // pe[j][n]: j = sample 0..63, n = dim 0..255
        int j = t >> 8, d = t & 255;
        float ang = (float)j * expf(-((float)(d >> 1)) * (9.210340371976184f / 128.0f));
        unsigned short pb = f2bf((d & 1) ? cosf(ang) : sinf(ang));
        ws[WS_WQ + d * KAUG + 256 + j] = pb;
        ws[WS_WK + d * KAUG + 256 + j] = pb;
        ws[WS_WV + d * KAUG + 256 + j] = pb;
    }
}

#define MFMA(d, a, b) d = __builtin_amdgcn_mfma_f32_16x16x32_bf16(             \
        __builtin_bit_cast(bf16x8, a), __builtin_bit_cast(bf16x8, b), d, 0, 0, 0)

// Cooperative stage: 64x256 fp32 -> bf16 LDS tile [64][STR_W], ONCE per block.
// 512 threads: thread handles row tid>>3, 32-col chunk (tid&7)*32.
// 8 coalesced f32x4 loads -> 4 v_perm-packed us8 -> 4 ds_write_b128.
#define STAGE(Xp, dst)                                                         \
    {                                                                          \
        int _r = tid >> 3, _c = (tid & 7) << 5;                                \
        const f32x4* _sp = (const f32x4*)((Xp) + _r * DD + _c);                \
        unsigned short* _dp = (dst) + _r * STR_W + _c;                         \
        _Pragma("unroll")                                                      \
        for (int _j = 0; _j < 4; ++_j) {                                       \
            f32x4 _a = _sp[2 * _j], _b = _sp[2 * _j + 1];                      \
            u32x4 _w;                                                          \
            _w[0] = packbf2(_a.x, _a.y); _w[1] = packbf2(_a.z, _a.w);          \
            _w[2] = packbf2(_b.x, _b.y); _w[3] = packbf2(_b.z, _b.w);          \
            *(us8*)(_dp + _j * 8) = __builtin_bit_cast(us8, _w);               \
        }                                                                      \
    }

// Projection from LDS-staged A: acc[4][2], all 8 waves, 32 cols each (n0h).
// A-fragments: 4 ds_read_b128/iter (rows l..48+l). B: 2 global (L2-hot W).
// pe tail: one-hot A (synthesized), B hoisted above loop.
// Entire body braced: locals are block-scoped (macro used 3x per function).
#define PROJECT_LDS(sX, Wp)                                                    \
    {                                                                          \
        us8 _tp0 = *(const us8*)((Wp) + (n0h + l) * KAUG + 256 + koff);        \
        us8 _tp1 = *(const us8*)((Wp) + (n0h + 16 + l) * KAUG + 256 + koff);   \
        us8 _tr0 = *(const us8*)((Wp) + (n0h + l) * KAUG + 288 + koff);        \
        us8 _tr1 = *(const us8*)((Wp) + (n0h + 16 + l) * KAUG + 288 + koff);   \
        _Pragma("unroll")                                                      \
        for (int k0 = 0; k0 < DD; k0 += 32) {                                  \
            us8 a0 = *(const us8*)((sX) + (l) * STR_W + k0 + koff);            \
            us8 a1 = *(const us8*)((sX) + (16 + l) * STR_W + k0 + koff);       \
            us8 a2 = *(const us8*)((sX) + (32 + l) * STR_W + k0 + koff);       \
            us8 a3 = *(const us8*)((sX) + (48 + l) * STR_W + k0 + koff);       \
            us8 b0 = *(const us8*)((Wp) + (n0h + l) * KAUG + k0 + koff);       \
            us8 b1 = *(const us8*)((Wp) + (n0h + 16 + l) * KAUG + k0 + koff);  \
            MFMA(acc[0][0], a0, b0); MFMA(acc[0][1], a0, b1);                  \
            MFMA(acc[1][0], a1, b0); MFMA(acc[1][1], a1, b1);                  \
            MFMA(acc[2][0], a2, b0); MFMA(acc[2][1], a2, b1);                  \
            MFMA(acc[3][0], a3, b0); MFMA(acc[3][1], a3, b1);                  \
        }                                                                      \
        MFMA(acc[0][0], idA, _tp0); MFMA(acc[0][1], idA, _tp1);                \
        MFMA(acc[1][0], idB, _tp0); MFMA(acc[1][1], idB, _tp1);                \
        MFMA(acc[2][0], idA, _tr0); MFMA(acc[2][1], idA, _tr1);                \
        MFMA(acc[3][0], idB, _tr0); MFMA(acc[3][1], idB, _tr1);                \
    }

#define ZERO_ACC                                                               \
    _Pragma("unroll")                                                          \
    for (int _i = 0; _i < 4; ++_i)                                             \
        _Pragma("unroll")                                                      \
        for (int _j = 0; _j < 2; ++_j) acc[_i][_j] = (f32x4){0.f, 0.f, 0.f, 0.f};

// Store acc[4][2] as bf16 into dst[64][STR_W], cols n0h..n0h+31
#define STORE_C32(dst)                                                         \
    _Pragma("unroll")                                                          \
    for (int mt = 0; mt < 4; ++mt)                                             \
        _Pragma("unroll")                                                      \
        for (int nt = 0; nt < 2; ++nt) {                                       \
            int col = n0h + nt * 16 + l;                                       \
            _Pragma("unroll")                                                  \
            for (int r = 0; r < 4; ++r)                                        \
                (dst)[(mt * 16 + (quad << 2) + r) * STR_W + col] = f2bf(acc[mt][nt][r]); \
        }

// 512 threads = 8 waves. LDS-staged inputs (loaded ONCE, not once per wave):
//   stage k->sB | kp(sB->regs)->sB | stage q->sA | qp->sA |
//   S+softmax(w0-3) || v->regs(w4-7) | vbf->sA | vp->vpT(sA) | PV->sB | Wo->sA | epilogue
// LDS 79872 B -> 2 blocks/CU, 16 waves/CU.
__global__ __launch_bounds__(512, 4)
void attn_kernel(const float* __restrict__ qg_, const float* __restrict__ kg_,
                 const float* __restrict__ vg_, const unsigned short* __restrict__ ws,
                 const float* __restrict__ bo, float* __restrict__ outg) {
    __shared__ __attribute__((aligned(16))) char smem[LDS_TOTAL];
    unsigned short* sA = (unsigned short*)(smem + OFF_A);
    unsigned short* sB = (unsigned short*)(smem + OFF_B);
    unsigned short* sP = (unsigned short*)(smem + OFF_P);

    const unsigned short* Wq = ws + WS_WQ;
    const unsigned short* Wk = ws + WS_WK;
    const unsigned short* Wv = ws + WS_WV;
    const unsigned short* Wo = ws + WS_WO;

    const int tid  = threadIdx.x;
    const int w    = tid >> 6;        // wave 0..7
    const int whi  = w >> 2;          // wave group
    const int lane = tid & 63;
    const int quad = lane >> 4;
    const int l    = lane & 15;
    const int n0h  = w << 5;          // this wave's 32-col chunk
    const int koff = quad << 3;

    // one-hot A fragments for the augmented pe tail (no loads):
    unsigned int w1 = (l & 1) ? 0x3F800000u : 0x00003F80u;  // bf16 1.0 hi/lo half
    int dw = (l >> 1) & 3;
    bool cA = (quad == (l >> 3));        // j_local = l
    bool cB = (quad == 2 + (l >> 3));    // j_local = 16+l
    u32x4 eA, eB;
    eA[0] = (cA && dw == 0) ? w1 : 0u; eA[1] = (cA && dw == 1) ? w1 : 0u;
    eA[2] = (cA && dw == 2) ? w1 : 0u; eA[3] = (cA && dw == 3) ? w1 : 0u;
    eB[0] = (cB && dw == 0) ? w1 : 0u; eB[1] = (cB && dw == 1) ? w1 : 0u;
    eB[2] = (cB && dw == 2) ? w1 : 0u; eB[3] = (cB && dw == 3) ? w1 : 0u;
    us8 idA = __builtin_bit_cast(us8, eA);
    us8 idB = __builtin_bit_cast(us8, eB);

    const size_t base = (size_t)blockIdx.x * (SS * DD);
    const float* qg = qg_ + base;
    const float* kg = kg_ + base;
    const float* vg = vg_ + base;
    float* og = outg + base;

    f32x4 acc[4][2];

    // ---- stage kbf -> sB ----
    STAGE(kg, sB)
    __syncthreads();  // S1: kbf visible

    // ---- kp = kbf@Wk^T (+pe) : A from LDS ----
    ZERO_ACC
    PROJECT_LDS(sB, Wk)
    __syncthreads();  // S2: all kbf reads done
    STORE_C32(sB)     // overwrite staging buffer with kp

    // ---- stage qbf -> sA (independent of sB) ----
    STAGE(qg, sA)
    __syncthreads();  // S3: qbf + kp visible

    // ---- qp = qbf@Wq^T (+pe) ----
    ZERO_ACC
    PROJECT_LDS(sA, Wq)
    __syncthreads();  // S4: all qbf reads done
    STORE_C32(sA)     // qp -> sA
    __syncthreads();  // S5: qp visible

    // ---- S = qp@kp^T + softmax (waves 0-3) || v -> regs (waves 4-7) ----
    us8 vr[8];
    if (whi == 0) {
        f32x4 s0 = {0.f,0.f,0.f,0.f}, s1 = {0.f,0.f,0.f,0.f};
        f32x4 s2 = {0.f,0.f,0.f,0.f}, s3 = {0.f,0.f,0.f,0.f};
        #pragma unroll
        for (int k0 = 0; k0 < DD; k0 += 32) {
            us8 a  = *(const us8*)(sA + (w * 16 + l) * STR_W + k0 + koff);
            us8 b0 = *(const us8*)(sB + (l) * STR_W + k0 + koff);
            us8 b1 = *(const us8*)(sB + (16 + l) * STR_W + k0 + koff);
            us8 b2 = *(const us8*)(sB + (32 + l) * STR_W + k0 + koff);
            us8 b3 = *(const us8*)(sB + (48 + l) * STR_W + k0 + koff);
            MFMA(s0, a, b0); MFMA(s1, a, b1); MFMA(s2, a, b2); MFMA(s3, a, b3);
        }
        #pragma unroll
        for (int r = 0; r < 4; ++r) {
            float v0 = s0[r] * 0.0625f, v1 = s1[r] * 0.0625f;
            float v2 = s2[r] * 0.0625f, v3 = s3[r] * 0.0625f;
            float mx = fmaxf(fmaxf(v0, v1), fmaxf(v2, v3));
            #pragma unroll
            for (int d = 1; d <= 8; d <<= 1) mx = fmaxf(mx, __shfl_xor(mx, d));
            float e0 = __expf(v0 - mx), e1 = __expf(v1 - mx);
            float e2 = __expf(v2 - mx), e3 = __expf(v3 - mx);
            float sm = e0 + e1 + e2 + e3;
            #pragma unroll
            for (int d = 1; d <= 8; d <<= 1) sm += __shfl_xor(sm, d);
            float inv = 1.0f / sm;
            int row = w * 16 + (quad << 2) + r;
            sP[row * STR_T + l]      = f2bf(e0 * inv);
            sP[row * STR_T + 16 + l] = f2bf(e1 * inv);
            sP[row * STR_T + 32 + l] = f2bf(e2 * inv);
            sP[row * STR_T + 48 + l] = f2bf(e3 * inv);
        }
    } else {
        // waves 4-7: load v (16 rows each) into regs, bf16-packed; spill after S
        int vrow = ((w - 4) << 4) + l;     // 0..63
        int vcb  = quad << 6;              // 64-col chunk
        const f32x4* vp = (const f32x4*)(vg + vrow * DD + vcb);
        #pragma unroll
        for (int j = 0; j < 8; ++j) {
            f32x4 ua = vp[2 * j], ub = vp[2 * j + 1];
            u32x4 wv;
            wv[0] = packbf2(ua.x, ua.y); wv[1] = packbf2(ua.z, ua.w);
            wv[2] = packbf2(ub.x, ub.y); wv[3] = packbf2(ub.z, ub.w);
            vr[j] = __builtin_bit_cast(us8, wv);
        }
    }
    __syncthreads();  // S6: S-phase LDS reads done; sP complete

    // ---- vbf -> sA (waves 4-7 spill regs; qp dead) ----
    if (whi) {
        int vrow = ((w - 4) << 4) + l;
        int vcb  = quad << 6;
        #pragma unroll
        for (int j = 0; j < 8; ++j)
            *(us8*)(sA + vrow * STR_W + vcb + 8 * j) = vr[j];
    }
    __syncthreads();  // S7: vbf visible

    // ---- vp = vbf@Wv^T (+pe) ----
    ZERO_ACC
    PROJECT_LDS(sA, Wv)
    __syncthreads();  // S8: all vbf reads done
    // transpose-write vpT into sA [256][STR_T]
    #pragma unroll
    for (int mt = 0; mt < 4; ++mt)
        #pragma unroll
        for (int nt = 0; nt < 2; ++nt) {
            int col = n0h + nt * 16 + l;            // d index = vpT row
            int rbase = mt * 16 + (quad << 2);
            us4 pk;
            #pragma unroll
            for (int r = 0; r < 4; ++r)
                pk[r] = f2bf(acc[mt][nt][r]);
            *(us4*)(sA + col * STR_T + rbase) = pk;
        }
    __syncthreads();  // S9: vpT visible

    // ---- attn-out = P @ vp -> sB (cols n0h..n0h+31) ----
    {
        ZERO_ACC
        #pragma unroll
        for (int k0 = 0; k0 < 64; k0 += 32) {
            us8 a0 = *(const us8*)(sP + (l) * STR_T + k0 + koff);
            us8 a1 = *(const us8*)(sP + (16 + l) * STR_T + k0 + koff);
            us8 a2 = *(const us8*)(sP + (32 + l) * STR_T + k0 + koff);
            us8 a3 = *(const us8*)(sP + (48 + l) * STR_T + k0 + koff);
            us8 b0 = *(const us8*)(sA + (n0h + l) * STR_T + k0 + koff);
            us8 b1 = *(const us8*)(sA + (n0h + 16 + l) * STR_T + k0 + koff);
            MFMA(acc[0][0], a0, b0); MFMA(acc[0][1], a0, b1);
            MFMA(acc[1][0], a1, b0); MFMA(acc[1][1], a1, b1);
            MFMA(acc[2][0], a2, b0); MFMA(acc[2][1], a2, b1);
            MFMA(acc[3][0], a3, b0); MFMA(acc[3][1], a3, b1);
        }
        __syncthreads();  // S10: vpT reads done (sB kp dead since S6)
        STORE_C32(sB)     // attn-out -> sB
    }
    __syncthreads();  // S11: attn-out visible

    // ---- y' = gelu(attn-out @ Wo^T + bo) -> sA ----
    {
        ZERO_ACC
        #pragma unroll
        for (int k0 = 0; k0 < DD; k0 += 32) {
            us8 a0 = *(const us8*)(sB + (l) * STR_W + k0 + koff);
            us8 a1 = *(const us8*)(sB + (16 + l) * STR_W + k0 + koff);
            us8 a2 = *(const us8*)(sB + (32 + l) * STR_W + k0 + koff);
            us8 a3 = *(const us8*)(sB + (48 + l) * STR_W + k0 + koff);
            us8 b0 = *(const us8*)(Wo + (n0h + l) * DD + k0 + koff);
            us8 b1 = *(const us8*)(Wo + (n0h + 16 + l) * DD + k0 + koff);
            MFMA(acc[0][0], a0, b0); MFMA(acc[0][1], a0, b1);
            MFMA(acc[1][0], a1, b0); MFMA(acc[1][1], a1, b1);
            MFMA(acc[2][0], a2, b0); MFMA(acc[2][1], a2, b1);
            MFMA(acc[3][0], a3, b0); MFMA(acc[3][1], a3, b1);
        }
        __syncthreads();  // S12: vpT reads (sA) done before gelu overwrite
        #pragma unroll
        for (int nt = 0; nt < 2; ++nt) {
            int col = n0h + nt * 16 + l;
            float bias = bo[col];
            #pragma unroll
            for (int mt = 0; mt < 4; ++mt) {
                #pragma unroll
                for (int r = 0; r < 4; ++r) {
                    int row = mt * 16 + (quad << 2) + r;
                    float y = acc[mt][nt][r] + bias;
                    // tanh-approx GELU: y*sigmoid(2u), max dev ~3e-4
                    float u = 1.5957691216f * y * (1.0f + 0.044715f * y * y);
                    float g = y / (1.0f + __expf(-u));
                    sA[row * STR_W + col] = f2bf(g);
                }
            }
        }
    }
    __syncthreads();  // S13: gelu-out visible

    // ---- coalesced epilogue: out = gelu-out + q ----
    #pragma unroll
    for (int s = 0; s < 8; ++s) {
        int f = s * 2048 + tid * 4;
        int row = f >> 8, col = f & 255;
        us4 gb = *(const us4*)(sA + row * STR_W + col);
        float4 qv = *(const float4*)(qg + f);
        float4 o;
        o.x = bf2f(gb[0]) + qv.x;
        o.y = bf2f(gb[1]) + qv.y;
        o.z = bf2f(gb[2]) + qv.z;
        o.w = bf2f(gb[3]) + qv.w;
        *(float4*)(og + f) = o;
    }
}

extern "C" void kernel_launch(void* const* d_in, const int* in_sizes, int n_in,
                              void* d_out, int out_size, void* d_ws, size_t ws_size,
                              hipStream_t stream) {
    const float* q  = (const float*)d_in[0];
    const float* k  = (const float*)d_in[1];
    const float* v  = (const float*)d_in[2];
    const float* Wq = (const float*)d_in[3];
    const float* Wk = (const float*)d_in[4];
    const float* Wv = (const float*)d_in[5];
    const float* Wo = (const float*)d_in[6];
    const float* bo = (const float*)d_in[7];
    unsigned short* ws = (unsigned short*)d_ws;  // augmented bf16 weights (pe folded)

    prep_kernel<<<256, 256, 0, stream>>>(Wq, Wk, Wv, Wo, ws);
    attn_kernel<<<NVIEWS, 512, 0, stream>>>(q, k, v, ws, bo, (float*)d_out);
}